// Round 1
// baseline (425.267 us; speedup 1.0000x reference)
//
#include <hip/hip_runtime.h>
#include <stdint.h>

// Problem: out[M,N] = x[M,K] @ dequant(W_q_packed)[K,N] + bias[N]
// M=N=K=4096, 4-bit nibbles packed 8/int32 along K, GROUP=128 rows per scale.
// Strategy: ws holds xb (bf16 x, 32MB) and wt (bf16 W^T, N-major, 32MB);
// then m97-style bf16 MFMA GEMM (128x128 tile, 16x16x32 MFMA, global_load_lds).

#define M_DIM 4096
#define N_DIM 4096
#define K_DIM 4096

typedef __attribute__((ext_vector_type(8))) short short8;
typedef __attribute__((ext_vector_type(4))) float f32x4;

__device__ __forceinline__ unsigned short f2bf(float f) {
  uint32_t u = __builtin_bit_cast(uint32_t, f);
  u += 0x7fffu + ((u >> 16) & 1u);   // round-to-nearest-even
  return (unsigned short)(u >> 16);
}

// ---------- kernel 1: x fp32 -> bf16 ----------
__global__ __launch_bounds__(256) void cvt_x_kernel(const float* __restrict__ x,
                                                    unsigned short* __restrict__ xb) {
  const int total = (M_DIM * K_DIM) / 4;   // 4M float4
  const float4* x4 = (const float4*)x;
  ushort4* o4 = (ushort4*)xb;
  for (int i = blockIdx.x * 256 + threadIdx.x; i < total; i += gridDim.x * 256) {
    float4 v = x4[i];
    ushort4 o;
    o.x = f2bf(v.x); o.y = f2bf(v.y); o.z = f2bf(v.z); o.w = f2bf(v.w);
    o4[i] = o;
  }
}

// ---------- kernel 2: dequant + transpose -> W^T (N x K) bf16 ----------
// tile: 32 n-cols x 64 packed-rows (= 512 k). LDS cells 16B (8 bf16 along k).
// XOR swizzle keeps both LDS phases conflict-free.
__global__ __launch_bounds__(256) void dequant_kernel(const int* __restrict__ Wq,
                                                      const float* __restrict__ scales,
                                                      const float* __restrict__ zeros,
                                                      unsigned short* __restrict__ wt) {
  __shared__ uint4 Ts[32 * 64];  // 32 KB
  const int tid = threadIdx.x;
  const int n0 = blockIdx.x * 32;
  const int gk0 = blockIdx.y * 64;

#pragma unroll
  for (int p = 0; p < 8; ++p) {
    int e = p * 256 + tid;          // 0..2047
    int n_l = e & 31;
    int gk_l = e >> 5;              // 0..63
    int gk = gk0 + gk_l;
    int n = n0 + n_l;
    int g = gk >> 4;                // group = (gk*8)/128
    uint32_t q = (uint32_t)Wq[gk * N_DIM + n];
    float s = scales[g * N_DIM + n];
    float z = zeros[g * N_DIM + n];
    unsigned short b[8];
#pragma unroll
    for (int j = 0; j < 8; ++j) {
      float f = ((float)((q >> (4 * j)) & 15u) - z) * s;
      b[j] = f2bf(f);
    }
    uint4 cell;
    cell.x = (uint32_t)b[0] | ((uint32_t)b[1] << 16);
    cell.y = (uint32_t)b[2] | ((uint32_t)b[3] << 16);
    cell.z = (uint32_t)b[4] | ((uint32_t)b[5] << 16);
    cell.w = (uint32_t)b[6] | ((uint32_t)b[7] << 16);
    Ts[n_l * 64 + (gk_l ^ (n_l & 7))] = cell;
  }
  __syncthreads();
  uint4* dst = (uint4*)wt;  // row n has K_DIM/8 = 512 cells
#pragma unroll
  for (int p = 0; p < 8; ++p) {
    int n_l = p * 4 + (tid >> 6);
    int gk_l = tid & 63;
    uint4 cell = Ts[n_l * 64 + (gk_l ^ (n_l & 7))];
    dst[(size_t)(n0 + n_l) * (K_DIM / 8) + (gk0 + gk_l)] = cell;
  }
}

// ---------- kernel 3: bf16 GEMM, C = A @ Bt^T + bias ----------
// A: M x K bf16 row-major. Bt: N x K bf16 row-major. 128x128 block tile,
// 4 waves in 2x2, each wave 64x64 via 4x4 grid of 16x16x32 MFMA.
// LDS layout: 16B cells [k-chunk(0..3)][row(0..127)] -> both global_load_lds
// staging and ds_read_b128 fragment reads are stride-1.
__global__ __launch_bounds__(256) void gemm_bt_kernel(const unsigned short* __restrict__ A,
                                                      const unsigned short* __restrict__ Bt,
                                                      const float* __restrict__ bias,
                                                      float* __restrict__ C) {
  __shared__ short8 As[512];  // 8 KB
  __shared__ short8 Bs[512];  // 8 KB
  const int tid = threadIdx.x;
  const int lane = tid & 63;
  const int w = tid >> 6;
  const int wm = w >> 1, wn = w & 1;
  const int m0 = blockIdx.y * 128;
  const int n0 = blockIdx.x * 128;

  // staging cell indices: two 64-cell chunks per wave, covering 512 cells
  const int sidx0 = w * 128 + lane;
  const int sidx1 = w * 128 + 64 + lane;
  const int ar0 = sidx0 & 127, ac0 = sidx0 >> 7;
  const int ar1 = sidx1 & 127, ac1 = sidx1 >> 7;
  const unsigned short* ap0 = A + (size_t)(m0 + ar0) * K_DIM + ac0 * 8;
  const unsigned short* ap1 = A + (size_t)(m0 + ar1) * K_DIM + ac1 * 8;
  const unsigned short* bp0 = Bt + (size_t)(n0 + ar0) * K_DIM + ac0 * 8;
  const unsigned short* bp1 = Bt + (size_t)(n0 + ar1) * K_DIM + ac1 * 8;

  f32x4 acc[4][4] = {};

  const int fr = lane & 15;   // m (A) / n (B) within 16-tile
  const int fc = lane >> 4;   // k-chunk
  const int a_base = fc * 128 + wm * 64 + fr;
  const int b_base = fc * 128 + wn * 64 + fr;

  for (int kk = 0; kk < K_DIM / 32; ++kk) {
    const int k0 = kk * 32;
    __syncthreads();  // all waves done reading previous tile
    __builtin_amdgcn_global_load_lds(
        (const __attribute__((address_space(1))) void*)(ap0 + k0),
        (__attribute__((address_space(3))) void*)&As[sidx0], 16, 0, 0);
    __builtin_amdgcn_global_load_lds(
        (const __attribute__((address_space(1))) void*)(ap1 + k0),
        (__attribute__((address_space(3))) void*)&As[sidx1], 16, 0, 0);
    __builtin_amdgcn_global_load_lds(
        (const __attribute__((address_space(1))) void*)(bp0 + k0),
        (__attribute__((address_space(3))) void*)&Bs[sidx0], 16, 0, 0);
    __builtin_amdgcn_global_load_lds(
        (const __attribute__((address_space(1))) void*)(bp1 + k0),
        (__attribute__((address_space(3))) void*)&Bs[sidx1], 16, 0, 0);
    __syncthreads();  // compiler drains vmcnt(0) before s_barrier

    short8 af[4], bv[4];
#pragma unroll
    for (int mi = 0; mi < 4; ++mi) af[mi] = As[a_base + mi * 16];
#pragma unroll
    for (int ni = 0; ni < 4; ++ni) bv[ni] = Bs[b_base + ni * 16];
#pragma unroll
    for (int mi = 0; mi < 4; ++mi)
#pragma unroll
      for (int ni = 0; ni < 4; ++ni)
        acc[mi][ni] = __builtin_amdgcn_mfma_f32_16x16x32_bf16(af[mi], bv[ni], acc[mi][ni], 0, 0, 0);
  }

  // epilogue: C/D layout col=lane&15, row=(lane>>4)*4+reg
  const int r0 = (lane >> 4) * 4;
#pragma unroll
  for (int ni = 0; ni < 4; ++ni) {
    const int gn = n0 + wn * 64 + ni * 16 + fr;
    const float bvv = bias[gn];
#pragma unroll
    for (int mi = 0; mi < 4; ++mi) {
      const int gm = m0 + wm * 64 + mi * 16 + r0;
#pragma unroll
      for (int r = 0; r < 4; ++r)
        C[(size_t)(gm + r) * N_DIM + gn] = acc[mi][ni][r] + bvv;
    }
  }
}

extern "C" void kernel_launch(void* const* d_in, const int* in_sizes, int n_in,
                              void* d_out, int out_size, void* d_ws, size_t ws_size,
                              hipStream_t stream) {
  const float* x = (const float*)d_in[0];
  const int* wq = (const int*)d_in[1];
  const float* sc = (const float*)d_in[2];
  const float* zr = (const float*)d_in[3];
  const float* bias = (const float*)d_in[4];
  float* out = (float*)d_out;

  unsigned short* xb = (unsigned short*)d_ws;                               // 32 MB
  unsigned short* wt = (unsigned short*)((char*)d_ws + (size_t)M_DIM * K_DIM * 2);  // +32 MB

  cvt_x_kernel<<<dim3(2048), dim3(256), 0, stream>>>(x, xb);
  dequant_kernel<<<dim3(N_DIM / 32, (K_DIM / 8) / 64), dim3(256), 0, stream>>>(wq, sc, zr, wt);
  gemm_bt_kernel<<<dim3(N_DIM / 128, M_DIM / 128), dim3(256), 0, stream>>>(xb, wt, bias, out);
}

// Round 2
// 306.051 us; speedup vs baseline: 1.3895x; 1.3895x over previous
//
#include <hip/hip_runtime.h>
#include <stdint.h>

// out[M,N] = x[M,K] @ dequant(W_q_packed)[K,N] + bias[N]
// M=N=K=4096, 4-bit nibbles packed 8/int32 along K, GROUP=128.
// ws: xb (bf16 x, 32MB) + wt (bf16 W^T N-major, 32MB); then m97-style bf16
// MFMA GEMM. R2 fix: LDS cells [row][kc] + XOR swizzle -> staging loads are
// 64B-coalesced AND ds_read_b128 fragment reads are 2-way (free).

#define M_DIM 4096
#define N_DIM 4096
#define K_DIM 4096

typedef __attribute__((ext_vector_type(8))) short short8;
typedef __attribute__((ext_vector_type(4))) float f32x4;

__device__ __forceinline__ unsigned short f2bf(float f) {
  uint32_t u = __builtin_bit_cast(uint32_t, f);
  u += 0x7fffu + ((u >> 16) & 1u);   // round-to-nearest-even
  return (unsigned short)(u >> 16);
}

// ---------- kernel 1: x fp32 -> bf16 ----------
__global__ __launch_bounds__(256) void cvt_x_kernel(const float* __restrict__ x,
                                                    unsigned short* __restrict__ xb) {
  const int total = (M_DIM * K_DIM) / 4;
  const float4* x4 = (const float4*)x;
  ushort4* o4 = (ushort4*)xb;
  for (int i = blockIdx.x * 256 + threadIdx.x; i < total; i += gridDim.x * 256) {
    float4 v = x4[i];
    ushort4 o;
    o.x = f2bf(v.x); o.y = f2bf(v.y); o.z = f2bf(v.z); o.w = f2bf(v.w);
    o4[i] = o;
  }
}

// ---------- kernel 2: dequant + transpose -> W^T (N x K) bf16 ----------
__global__ __launch_bounds__(256) void dequant_kernel(const int* __restrict__ Wq,
                                                      const float* __restrict__ scales,
                                                      const float* __restrict__ zeros,
                                                      unsigned short* __restrict__ wt) {
  __shared__ uint4 Ts[32 * 64];  // 32 KB
  const int tid = threadIdx.x;
  const int n0 = blockIdx.x * 32;
  const int gk0 = blockIdx.y * 64;

#pragma unroll
  for (int p = 0; p < 8; ++p) {
    int e = p * 256 + tid;
    int n_l = e & 31;
    int gk_l = e >> 5;
    int gk = gk0 + gk_l;
    int n = n0 + n_l;
    int g = gk >> 4;                // group = (gk*8)/128
    uint32_t q = (uint32_t)Wq[gk * N_DIM + n];
    float s = scales[g * N_DIM + n];
    float z = zeros[g * N_DIM + n];
    unsigned short b[8];
#pragma unroll
    for (int j = 0; j < 8; ++j) {
      float f = ((float)((q >> (4 * j)) & 15u) - z) * s;
      b[j] = f2bf(f);
    }
    uint4 cell;
    cell.x = (uint32_t)b[0] | ((uint32_t)b[1] << 16);
    cell.y = (uint32_t)b[2] | ((uint32_t)b[3] << 16);
    cell.z = (uint32_t)b[4] | ((uint32_t)b[5] << 16);
    cell.w = (uint32_t)b[6] | ((uint32_t)b[7] << 16);
    Ts[n_l * 64 + (gk_l ^ (n_l & 7))] = cell;
  }
  __syncthreads();
  uint4* dst = (uint4*)wt;
#pragma unroll
  for (int p = 0; p < 8; ++p) {
    int n_l = p * 4 + (tid >> 6);
    int gk_l = tid & 63;
    uint4 cell = Ts[n_l * 64 + (gk_l ^ (n_l & 7))];
    dst[(size_t)(n0 + n_l) * (K_DIM / 8) + (gk0 + gk_l)] = cell;
  }
}

// ---------- kernel 3: bf16 GEMM, C = A @ Bt^T + bias ----------
// 128x128 tile, 4 waves 2x2, each wave 64x64 via 4x4 of 16x16x32 MFMA, BK=32.
// LDS: 16B cells, cell(row,kc) = row*4 + (kc ^ ((row>>1)&3)).
//  - staging: lane c of a 64-cell window fetches (row=c>>2, kc=(c&3)^((row>>1)&3))
//    -> each 4-lane group covers one contiguous 64B row segment (coalesced);
//  - fragment ds_read_b128: bank start = (fr&1)*16 + (fc^((fr>>1)&3))*4
//    -> 8 distinct bank-quads x2 over 16 lanes = 2-way = free (m136).
__global__ __launch_bounds__(256) void gemm_bt_kernel(const unsigned short* __restrict__ A,
                                                      const unsigned short* __restrict__ Bt,
                                                      const float* __restrict__ bias,
                                                      float* __restrict__ C) {
  __shared__ short8 As[512];  // 8 KB
  __shared__ short8 Bs[512];  // 8 KB
  const int tid = threadIdx.x;
  const int lane = tid & 63;
  const int w = tid >> 6;
  const int wm = w >> 1, wn = w & 1;
  const int m0 = blockIdx.y * 128;
  const int n0 = blockIdx.x * 128;

  // staging: two 64-cell windows per wave
  const int c0 = w * 128 + lane;
  const int c1 = c0 + 64;
  const int r0 = c0 >> 2, kc0 = (c0 & 3) ^ ((r0 >> 1) & 3);
  const int r1 = c1 >> 2, kc1 = (c1 & 3) ^ ((r1 >> 1) & 3);
  const unsigned short* ap0 = A + (size_t)(m0 + r0) * K_DIM + kc0 * 8;
  const unsigned short* ap1 = A + (size_t)(m0 + r1) * K_DIM + kc1 * 8;
  const unsigned short* bp0 = Bt + (size_t)(n0 + r0) * K_DIM + kc0 * 8;
  const unsigned short* bp1 = Bt + (size_t)(n0 + r1) * K_DIM + kc1 * 8;

  f32x4 acc[4][4] = {};

  const int fr = lane & 15;   // m (A) / n (B) within 16-tile
  const int fc = lane >> 4;   // k-chunk 0..3
  const int swz = fc ^ ((fr >> 1) & 3);
  const int a_base = (wm * 64 + fr) * 4 + swz;   // + mi*64
  const int b_base = (wn * 64 + fr) * 4 + swz;   // + ni*64

  for (int kk = 0; kk < K_DIM / 32; ++kk) {
    const int k0 = kk * 32;
    __syncthreads();
    __builtin_amdgcn_global_load_lds(
        (const __attribute__((address_space(1))) void*)(ap0 + k0),
        (__attribute__((address_space(3))) void*)&As[c0], 16, 0, 0);
    __builtin_amdgcn_global_load_lds(
        (const __attribute__((address_space(1))) void*)(ap1 + k0),
        (__attribute__((address_space(3))) void*)&As[c1], 16, 0, 0);
    __builtin_amdgcn_global_load_lds(
        (const __attribute__((address_space(1))) void*)(bp0 + k0),
        (__attribute__((address_space(3))) void*)&Bs[c0], 16, 0, 0);
    __builtin_amdgcn_global_load_lds(
        (const __attribute__((address_space(1))) void*)(bp1 + k0),
        (__attribute__((address_space(3))) void*)&Bs[c1], 16, 0, 0);
    __syncthreads();

    short8 af[4], bv[4];
#pragma unroll
    for (int mi = 0; mi < 4; ++mi) af[mi] = As[a_base + mi * 64];
#pragma unroll
    for (int ni = 0; ni < 4; ++ni) bv[ni] = Bs[b_base + ni * 64];
#pragma unroll
    for (int mi = 0; mi < 4; ++mi)
#pragma unroll
      for (int ni = 0; ni < 4; ++ni)
        acc[mi][ni] = __builtin_amdgcn_mfma_f32_16x16x32_bf16(af[mi], bv[ni], acc[mi][ni], 0, 0, 0);
  }

  // epilogue: C/D layout col=lane&15, row=(lane>>4)*4+reg
  const int rr = (lane >> 4) * 4;
#pragma unroll
  for (int ni = 0; ni < 4; ++ni) {
    const int gn = n0 + wn * 64 + ni * 16 + fr;
    const float bvv = bias[gn];
#pragma unroll
    for (int mi = 0; mi < 4; ++mi) {
      const int gm = m0 + wm * 64 + mi * 16 + rr;
#pragma unroll
      for (int r = 0; r < 4; ++r)
        C[(size_t)(gm + r) * N_DIM + gn] = acc[mi][ni][r] + bvv;
    }
  }
}

extern "C" void kernel_launch(void* const* d_in, const int* in_sizes, int n_in,
                              void* d_out, int out_size, void* d_ws, size_t ws_size,
                              hipStream_t stream) {
  const float* x = (const float*)d_in[0];
  const int* wq = (const int*)d_in[1];
  const float* sc = (const float*)d_in[2];
  const float* zr = (const float*)d_in[3];
  const float* bias = (const float*)d_in[4];
  float* out = (float*)d_out;

  unsigned short* xb = (unsigned short*)d_ws;
  unsigned short* wt = (unsigned short*)((char*)d_ws + (size_t)M_DIM * K_DIM * 2);

  cvt_x_kernel<<<dim3(2048), dim3(256), 0, stream>>>(x, xb);
  dequant_kernel<<<dim3(N_DIM / 32, (K_DIM / 8) / 64), dim3(256), 0, stream>>>(wq, sc, zr, wt);
  gemm_bt_kernel<<<dim3(N_DIM / 128, M_DIM / 128), dim3(256), 0, stream>>>(xb, wt, bias, out);
}